// Round 2
// baseline (511.151 us; speedup 1.0000x reference)
//
#include <hip/hip_runtime.h>

// Problem constants (fixed by the reference setup_inputs)
#define BB 4
#define CC 64
#define HH 512
#define WW 512
#define NN 2048
// slots = B * (H/16) * (W/16) = 4 * 32 * 32
#define SLOTS 4096

// d_ws layout: heads[SLOTS], nxt[NN], flag[1]  (flag=1 -> indices are int64)

__global__ void init_ws_kernel(int* __restrict__ heads, int* __restrict__ flag) {
    int i = blockIdx.x * blockDim.x + threadIdx.x;
    if (i < SLOTS) heads[i] = -1;
    if (i == 0) *flag = 1;   // assume int64 until proven otherwise
}

// If indices are int64 (little-endian), every odd int32 word is a zero high
// word (values < 512). If int32, the 3072 odd words hold random index values
// and cannot all be zero. Benign-race plain stores of 0.
__global__ void detect_dtype_kernel(const int* __restrict__ idx32,
                                    int* __restrict__ flag) {
    int i = blockIdx.x * blockDim.x + threadIdx.x;   // i < 3*NN/2 = 3072
    if (i < 3 * NN / 2) {
        if (idx32[2 * i + 1] != 0) *flag = 0;
    }
}

__global__ void build_lists_kernel(const int* __restrict__ idx,
                                   int* __restrict__ heads,
                                   int* __restrict__ nxt,
                                   const int* __restrict__ flag) {
    int n = blockIdx.x * blockDim.x + threadIdx.x;
    if (n < NN) {
        int b, hi, wi;
        if (*flag) {           // int64 indices: stride 2 int32 words, low word
            b  = idx[6 * n + 0];
            hi = idx[6 * n + 2];
            wi = idx[6 * n + 4];
        } else {               // int32 indices
            b  = idx[3 * n + 0];
            hi = idx[3 * n + 1];
            wi = idx[3 * n + 2];
        }
        int slot = (b << 10) | (hi << 5) | wi;   // b*1024 + hi*32 + wi
        nxt[n] = atomicExch(&heads[slot], n);
    }
}

// One thread per output float4. out = in + sum of covering patches.
__global__ __launch_bounds__(256) void scatter_add_kernel(
    const float4* __restrict__ in4,
    const float4* __restrict__ g4,
    const int* __restrict__ heads,
    const int* __restrict__ nxt,
    float4* __restrict__ out4)
{
    int e = blockIdx.x * 256 + threadIdx.x;      // e < B*C*H*(W/4) = 16,777,216
    const int w4 = e & 127;                      // W/4 = 128
    const int h  = (e >> 7) & 511;
    const int cb = e >> 16;                      // c + C*b
    const int c  = cb & 63;
    const int b  = cb >> 6;

    float4 v = in4[e];

    const int slot = (b << 10) | ((h >> 4) << 5) | (w4 >> 2);
    int n = heads[slot];
    if (n >= 0) {
        // gathered float4 index: n*4096 + c*64 + (h%16)*4 + (w4%4)
        const int goff4 = (c << 6) | ((h & 15) << 2) | (w4 & 3);
        do {
            float4 g = g4[n * 4096 + goff4];
            v.x += g.x; v.y += g.y; v.z += g.z; v.w += g.w;
            n = nxt[n];
        } while (n >= 0);
    }
    out4[e] = v;
}

// ---- Fallback path (only if d_ws is impossibly small): copy + atomic scatter ----
__global__ __launch_bounds__(256) void copy_kernel(const float4* __restrict__ in4,
                                                   float4* __restrict__ out4) {
    int e = blockIdx.x * 256 + threadIdx.x;
    out4[e] = in4[e];
}

__global__ __launch_bounds__(256) void atomic_scatter_kernel(
    const float* __restrict__ g,
    const int* __restrict__ idx,
    float* __restrict__ out)
{
    int i = blockIdx.x * 256 + threadIdx.x;      // i < N*C*16*16 = 33,554,432
    int n = i >> 14;                             // / 16384
    int r = i & 16383;
    int c  = r >> 8;
    int rr = (r >> 4) & 15;
    int w  = r & 15;
    int b  = idx[3 * n + 0];
    int hi = idx[3 * n + 1];
    int wi = idx[3 * n + 2];
    int off = ((b * CC + c) * HH + hi * 16 + rr) * WW + wi * 16 + w;
    atomicAdd(&out[off], g[i]);
}

extern "C" void kernel_launch(void* const* d_in, const int* in_sizes, int n_in,
                              void* d_out, int out_size, void* d_ws, size_t ws_size,
                              hipStream_t stream) {
    const float* inp      = (const float*)d_in[0];
    const float* gathered = (const float*)d_in[1];
    const int*   idx      = (const int*)d_in[2];
    float* out = (float*)d_out;

    const size_t ws_needed = (size_t)(SLOTS + NN + 1) * sizeof(int);

    if (ws_size >= ws_needed) {
        int* heads = (int*)d_ws;
        int* nxt   = heads + SLOTS;
        int* flag  = nxt + NN;
        init_ws_kernel<<<(SLOTS + 255) / 256, 256, 0, stream>>>(heads, flag);
        detect_dtype_kernel<<<(3 * NN / 2 + 255) / 256, 256, 0, stream>>>(idx, flag);
        build_lists_kernel<<<(NN + 255) / 256, 256, 0, stream>>>(idx, heads, nxt, flag);
        const int n_out4 = BB * CC * HH * (WW / 4);   // 16,777,216
        scatter_add_kernel<<<n_out4 / 256, 256, 0, stream>>>(
            (const float4*)inp, (const float4*)gathered, heads, nxt, (float4*)out);
    } else {
        const int n_out4 = BB * CC * HH * (WW / 4);
        copy_kernel<<<n_out4 / 256, 256, 0, stream>>>((const float4*)inp, (float4*)out);
        const int n_g = NN * CC * 16 * 16;            // 33,554,432
        atomic_scatter_kernel<<<n_g / 256, 256, 0, stream>>>(gathered, idx, out);
    }
}